// Round 11
// baseline (229.972 us; speedup 1.0000x reference)
//
#include <hip/hip_runtime.h>

// R18: best-of-breed recombination. Ledger across 11 rounds: totals pinned
// 226.6-229.9 while profiled components swung 150-190us; work INCREASES
// (+100us, R14/R16) track 1:1 but 10-20us component wins never surface ->
// timed-graph kernels run warm (L3) and much faster than cold-replay
// profiles; ~90us is fixed harness overhead. One systematic signal: the 3
// dbuf-GEMM rounds hold the 3 best totals (226.63/226.65/227.37). So: keep
// R17's 64q replay-safe attn (58.8us profiled, best) + R11's double-buffered
// GEMM (stage-next-before-compute, 1 barrier/K-step) + cast_all + proj.
// Pure recombination of verified pieces, no new schedule risk.
#define DIM 512
#define NQ 2048
#define MA 2048
#define MS 256
#define QSCALE 0.06375864651f  // 512^-0.5 * log2(e)

typedef __attribute__((ext_vector_type(8))) short bf16x8;
typedef __attribute__((ext_vector_type(4))) float f32x4;
typedef __attribute__((ext_vector_type(16))) float f32x16;

__device__ __forceinline__ ushort f2b(float f) {
    uint u = __float_as_uint(f);
    u = (u + 0x7fffu + ((u >> 16) & 1u)) >> 16;
    return (ushort)u;
}

__device__ __forceinline__ uint pk2bf(float a, float b) {
#if __has_builtin(__builtin_amdgcn_cvt_pk_bf16_f32)
    typedef __attribute__((ext_vector_type(2))) __bf16 bf2;
    bf2 r = __builtin_amdgcn_cvt_pk_bf16_f32(a, b);
    uint u;
    __builtin_memcpy(&u, &r, 4);
    return u;
#else
    return ((__float_as_uint(a) + 0x8000u) >> 16) |
           ((__float_as_uint(b) + 0x8000u) & 0xffff0000u);
#endif
}

__device__ __forceinline__ float fexp2(float x) {
#if __has_builtin(__builtin_amdgcn_exp2f)
    return __builtin_amdgcn_exp2f(x);
#else
    return exp2f(x);
#endif
}

__device__ __forceinline__ void gload16(const ushort* g, ushort* l) {
    __builtin_amdgcn_global_load_lds(
        (const __attribute__((address_space(1))) void*)g,
        (__attribute__((address_space(3))) void*)l, 16, 0, 0);
}

// ---- fused cast: 6 weights + x + ac + scx -> contiguous bf16 region ----
__global__ __launch_bounds__(256) void cast_all(const float* __restrict__ w0,
                                                const float* __restrict__ w1,
                                                const float* __restrict__ w2,
                                                const float* __restrict__ w3,
                                                const float* __restrict__ w4,
                                                const float* __restrict__ w5,
                                                const float* __restrict__ x,
                                                const float* __restrict__ ac,
                                                const float* __restrict__ scx,
                                                ushort* __restrict__ dst) {
    int i = blockIdx.x * 256 + threadIdx.x;  // float4 index, 2621440 total
    const float* s;
    int o;
    if (i < 393216) {
        int w = i >> 16;
        s = w < 3 ? (w == 0 ? w0 : (w == 1 ? w1 : w2))
                  : (w == 3 ? w3 : (w == 4 ? w4 : w5));
        o = i & 65535;
    } else if (i < 1441792) { s = x;   o = i - 393216; }
    else if (i < 2490368)   { s = ac;  o = i - 1441792; }
    else                    { s = scx; o = i - 2490368; }
    float4 v = ((const float4*)s)[o];
    ushort4 u;
    u.x = f2b(v.x); u.y = f2b(v.y); u.z = f2b(v.z); u.w = f2b(v.w);
    ((ushort4*)dst)[i] = u;
}

// ---- fused GEMM (R11 dbuf): C = A @ B^T + bias, 128x128 tile, BK=32 ----
// LDS double-buffer, single barrier per K-step, stage-next-before-compute.
struct GD {
    const ushort* A; const ushort* B; const float* bias; void* out;
    long sB, sO;
    int N, bx, by, blk0, biasrow, scaleq, outf32, pad;
};

__global__ __launch_bounds__(256) void gemm_fused(GD d0, GD d1, GD d2, GD d3, GD d4) {
    __shared__ ushort At[2][128 * 32];
    __shared__ ushort Bt[2][128 * 32];
    GD d = d0;
    int bid = blockIdx.x;
    if (bid >= d1.blk0) d = d1;
    if (bid >= d2.blk0) d = d2;
    if (bid >= d3.blk0) d = d3;
    if (bid >= d4.blk0) d = d4;
    int local = bid - d.blk0;
    int x = local % d.bx;
    int rem = local / d.bx;
    int y = rem % d.by;
    int z = rem / d.by;

    int t = threadIdx.x;
    int wv = t >> 6, ln = t & 63, l = ln & 15, g = ln >> 4;
    int wrow = wv & 1, wcol = wv >> 1;
    int row0 = x * 128, col0 = y * 128;
    int srow = t >> 2;
    int slot = (t & 3) * 8;
    int sko = ((t ^ srow) & 3) * 8;        // XOR-swizzled global k-chunk
    int kc8 = ((g ^ (l & 3)) & 3) * 8;     // reader un-swizzle
    const ushort* Ab = d.A;
    const ushort* Bb = d.B + (size_t)z * d.sB;
    int N = d.N;

    const ushort* Ar0 = Ab + (size_t)(row0 + srow) * 512 + sko;
    const ushort* Ar1 = Ab + (size_t)(row0 + srow + 64) * 512 + sko;
    const ushort* Br0 = Bb + (size_t)(col0 + srow) * 512 + sko;
    const ushort* Br1 = Bb + (size_t)(col0 + srow + 64) * 512 + sko;
    int so0 = srow * 32 + slot;
    int so1 = (srow + 64) * 32 + slot;

    f32x4 acc[4][4];
#pragma unroll
    for (int i = 0; i < 4; i++)
#pragma unroll
        for (int j = 0; j < 4; j++) acc[i][j] = (f32x4){0, 0, 0, 0};

    // prologue: stage K-step 0 into buf 0
    gload16(Ar0, At[0] + so0);
    gload16(Ar1, At[0] + so1);
    gload16(Br0, Bt[0] + so0);
    gload16(Br1, Bt[0] + so1);

#pragma unroll 2
    for (int k0 = 0; k0 < 512; k0 += 32) {
        int cur = (k0 >> 5) & 1;
        __syncthreads();  // drains loads issued one compute-phase ago
        if (k0 + 32 < 512) {  // issue next tile BEFORE computing current
            gload16(Ar0 + k0 + 32, At[cur ^ 1] + so0);
            gload16(Ar1 + k0 + 32, At[cur ^ 1] + so1);
            gload16(Br0 + k0 + 32, Bt[cur ^ 1] + so0);
            gload16(Br1 + k0 + 32, Bt[cur ^ 1] + so1);
        }
        bf16x8 ar[4], br[4];
#pragma unroll
        for (int i = 0; i < 4; i++)
            ar[i] = *(const bf16x8*)(At[cur] + (wrow * 64 + i * 16 + l) * 32 + kc8);
#pragma unroll
        for (int j = 0; j < 4; j++)
            br[j] = *(const bf16x8*)(Bt[cur] + (wcol * 64 + j * 16 + l) * 32 + kc8);
#pragma unroll
        for (int i = 0; i < 4; i++)
#pragma unroll
            for (int j = 0; j < 4; j++)
                acc[i][j] = __builtin_amdgcn_mfma_f32_16x16x32_bf16(ar[i], br[j], acc[i][j], 0, 0, 0);
    }
#pragma unroll
    for (int i = 0; i < 4; i++) {
#pragma unroll
        for (int j = 0; j < 4; j++) {
            int row = row0 + wrow * 64 + i * 16 + g * 4;
            int col = col0 + wcol * 64 + j * 16 + l;
#pragma unroll
            for (int r = 0; r < 4; r++) {
                float bv = d.biasrow ? d.bias[row + r] : d.bias[col];
                float o = acc[i][j][r] + bv;
                if (d.scaleq) o *= QSCALE;
                if (d.outf32)
                    ((float*)d.out + (size_t)z * d.sO)[(size_t)(row + r) * N + col] = o;
                else
                    ((ushort*)d.out + (size_t)z * d.sO)[(size_t)(row + r) * N + col] = f2b(o);
            }
        }
    }
}

// ---- attention inner loop: 64 q-rows/wave, R9 staging/layout verbatim ----
// Stride-72 LDS K/V dbuf, reg-staged, 1 barrier/tile. V-frag reads shared by
// both q-halves. PV folded per-c: pq[2][4] only.
__device__ __forceinline__ void attn_ctx64(const ushort* __restrict__ kg,
                                           const ushort* __restrict__ vg,
                                           int M, int nt, const bf16x8 (&aq)[2][4],
                                           ushort* __restrict__ Kl,
                                           ushort* __restrict__ Vl,
                                           f32x16 (&o)[4], float (&li)[2],
                                           int l5, int hi, int sr, int sc, int vbase) {
    bf16x8 k0 = *(const bf16x8*)kg;
    bf16x8 k1 = *(const bf16x8*)(kg + (size_t)32 * DIM);
    bf16x8 v0 = *(const bf16x8*)vg;
    bf16x8 v1 = *(const bf16x8*)(vg + (size_t)32 * M);
    __syncthreads();
    {   // tile 0 -> buf 0
        *(bf16x8*)(Kl + sr * 72 + sc) = k0;
        *(bf16x8*)(Kl + (sr + 32) * 72 + sc) = k1;
        union { bf16x8 v; uint2 h[2]; } cv;
        cv.v = v0;
        *(uint2*)(Vl + sr * 72 + vbase) = cv.h[0];
        *(uint2*)(Vl + sr * 72 + vbase + 8) = cv.h[1];
        cv.v = v1;
        *(uint2*)(Vl + (sr + 32) * 72 + vbase) = cv.h[0];
        *(uint2*)(Vl + (sr + 32) * 72 + vbase + 8) = cv.h[1];
    }
    if (nt > 1) {
        k0 = *(const bf16x8*)(kg + (size_t)64 * DIM);
        k1 = *(const bf16x8*)(kg + (size_t)96 * DIM);
        v0 = *(const bf16x8*)(vg + 64);
        v1 = *(const bf16x8*)(vg + (size_t)32 * M + 64);
    }
    for (int i = 0; i < nt; i++) {
        __syncthreads();
        if (i + 1 < nt) {
            ushort* Kb = Kl + ((i + 1) & 1) * (64 * 72);
            ushort* Vb = Vl + ((i + 1) & 1) * (64 * 72);
            *(bf16x8*)(Kb + sr * 72 + sc) = k0;
            *(bf16x8*)(Kb + (sr + 32) * 72 + sc) = k1;
            union { bf16x8 v; uint2 h[2]; } cv;
            cv.v = v0;
            *(uint2*)(Vb + sr * 72 + vbase) = cv.h[0];
            *(uint2*)(Vb + sr * 72 + vbase + 8) = cv.h[1];
            cv.v = v1;
            *(uint2*)(Vb + (sr + 32) * 72 + vbase) = cv.h[0];
            *(uint2*)(Vb + (sr + 32) * 72 + vbase + 8) = cv.h[1];
        }
        if (i + 2 < nt) {
            size_t off = (size_t)(i + 2) * 64;
            k0 = *(const bf16x8*)(kg + off * DIM);
            k1 = *(const bf16x8*)(kg + (off + 32) * DIM);
            v0 = *(const bf16x8*)(vg + off);
            v1 = *(const bf16x8*)(vg + (size_t)32 * M + off);
        }
        const ushort* Kc = Kl + (i & 1) * (64 * 72);
        const ushort* Vc = Vl + (i & 1) * (64 * 72);
#pragma unroll
        for (int c = 0; c < 2; c++) {
            bf16x8 kf[4];
#pragma unroll
            for (int kd = 0; kd < 4; kd++)
                kf[kd] = *(const bf16x8*)(Kc + (32 * c + l5) * 72 + kd * 16 + hi * 8);
            uint2 pq[2][4];
#pragma unroll
            for (int qh = 0; qh < 2; qh++) {
                f32x16 s;
#pragma unroll
                for (int ii = 0; ii < 16; ii++) s[ii] = 0.f;
#pragma unroll
                for (int kd = 0; kd < 4; kd++)
                    s = __builtin_amdgcn_mfma_f32_32x32x16_bf16(kf[kd], aq[qh][kd], s, 0, 0, 0);
#pragma unroll
                for (int m = 0; m < 4; m++) {
                    float p0 = fexp2(s[4 * m + 0]);
                    float p1 = fexp2(s[4 * m + 1]);
                    float p2 = fexp2(s[4 * m + 2]);
                    float p3 = fexp2(s[4 * m + 3]);
                    li[qh] += (p0 + p1) + (p2 + p3);
                    pq[qh][m].x = pk2bf(p0, p1);
                    pq[qh][m].y = pk2bf(p2, p3);
                }
            }
            // PV for this c's two k-slots; vf shared across both q-halves
#pragma unroll
            for (int kk = 0; kk < 2; kk++) {
                int kc = 2 * c + kk, m0 = 2 * kk;
                bf16x8 vf0 = *(const bf16x8*)(Vc + l5 * 72 + kc * 16 + hi * 8);
                bf16x8 vf1 = *(const bf16x8*)(Vc + (32 + l5) * 72 + kc * 16 + hi * 8);
#pragma unroll
                for (int qh = 0; qh < 2; qh++) {
                    union { bf16x8 v; uint u[4]; } w;
                    w.u[0] = pq[qh][m0].x;     w.u[1] = pq[qh][m0].y;
                    w.u[2] = pq[qh][m0 + 1].x; w.u[3] = pq[qh][m0 + 1].y;
                    o[qh * 2 + 0] = __builtin_amdgcn_mfma_f32_32x32x16_bf16(w.v, vf0, o[qh * 2 + 0], 0, 0, 0);
                    o[qh * 2 + 1] = __builtin_amdgcn_mfma_f32_32x32x16_bf16(w.v, vf1, o[qh * 2 + 1], 0, 0, 0);
                }
            }
        }
    }
}

// 512 threads: grp = ctx half, wave wg (0..3) owns 64 q-rows; block = 256 q.
// Exchange: two fully-unrolled rounds (static qh, rule #20) of 34-float
// slots living strictly in grp1's dead staging region (race discipline).
__global__ __launch_bounds__(512) void attn_kernel(const ushort* __restrict__ q,
                                                   const ushort* __restrict__ Ka,
                                                   const ushort* __restrict__ VTa,
                                                   const ushort* __restrict__ Ks,
                                                   const ushort* __restrict__ VTs,
                                                   ushort* __restrict__ y) {
    __shared__ ushort smem[2 * 18432];  // [grp][Kl 9216 | Vl 9216]
    int t = threadIdx.x;
    int grp = t >> 8;
    int tg = t & 255;
    int wg = tg >> 6;
    int ln = t & 63, l5 = ln & 31, hi = ln >> 5;
    ushort* Kl = smem + grp * 18432;
    ushort* Vl = Kl + 9216;
    float* osc = (float*)(smem + 18432);  // grp1 region ONLY: 256*34*4 B fits
    int h = blockIdx.y, bi = blockIdx.z;
    int q0 = blockIdx.x * 256 + wg * 64;
    bf16x8 aq[2][4];
#pragma unroll
    for (int qh = 0; qh < 2; qh++) {
        const ushort* qp = q + (size_t)(bi * NQ + q0 + qh * 32 + l5) * DIM + h * 64 + hi * 8;
#pragma unroll
        for (int kd = 0; kd < 4; kd++) aq[qh][kd] = *(const bf16x8*)(qp + kd * 16);
    }
    int sr = tg >> 3, sc = (tg & 7) * 8;
    int vbase = (sc >> 4) * 16 + ((sc >> 3) & 1) * 4;  // permuted V slot base

    f32x16 o[4];
#pragma unroll
    for (int k = 0; k < 4; k++)
#pragma unroll
        for (int i = 0; i < 16; i++) o[k][i] = 0.f;
    float li[2] = {0.f, 0.f};

    // audio (long) first: group grp handles ctx [grp*1024, grp*1024+1024)
    attn_ctx64(Ka + (size_t)bi * MA * DIM + (size_t)(grp * 1024 + sr) * DIM + h * 64 + sc,
               VTa + (size_t)bi * DIM * MA + (size_t)(h * 64 + sr) * MA + grp * 1024 + sc,
               MA, 16, aq, Kl, Vl, o, li, l5, hi, sr, sc, vbase);
    li[0] += __shfl_xor(li[0], 32);
    li[1] += __shfl_xor(li[1], 32);
    float yv[4][16];
    float* p = osc + tg * 34;
#pragma unroll
    for (int qh = 0; qh < 2; qh++) {   // FULL unroll: static qh (rule #20)
        __syncthreads();  // qh=0: staging reads done; qh=1: round-0 reads done
        if (grp) {
#pragma unroll
            for (int dn = 0; dn < 2; dn++)
#pragma unroll
                for (int r = 0; r < 8; r++)
                    *(float2*)(p + dn * 16 + 2 * r) =
                        (float2){o[qh * 2 + dn][2 * r], o[qh * 2 + dn][2 * r + 1]};
            p[32] = li[qh];
        }
        __syncthreads();  // partials visible
        if (!grp) {
#pragma unroll
            for (int dn = 0; dn < 2; dn++)
#pragma unroll
                for (int r = 0; r < 16; r++) o[qh * 2 + dn][r] += p[dn * 16 + r];
            li[qh] += p[32];
            float inv[16];
#pragma unroll
            for (int rg = 0; rg < 16; rg++)
                inv[rg] = 1.f / __shfl(li[qh], (rg & 3) + 8 * (rg >> 2) + 4 * hi);
#pragma unroll
            for (int dn = 0; dn < 2; dn++)
#pragma unroll
                for (int rg = 0; rg < 16; rg++)
                    yv[qh * 2 + dn][rg] = o[qh * 2 + dn][rg] * inv[rg];
        }
    }

#pragma unroll
    for (int k = 0; k < 4; k++)
#pragma unroll
        for (int i = 0; i < 16; i++) o[k][i] = 0.f;
    li[0] = li[1] = 0.f;
    // singer (short): group grp handles ctx [grp*128, grp*128+128)
    attn_ctx64(Ks + (size_t)bi * MS * DIM + (size_t)(grp * 128 + sr) * DIM + h * 64 + sc,
               VTs + (size_t)bi * DIM * MS + (size_t)(h * 64 + sr) * MS + grp * 128 + sc,
               MS, 2, aq, Kl, Vl, o, li, l5, hi, sr, sc, vbase);
    li[0] += __shfl_xor(li[0], 32);
    li[1] += __shfl_xor(li[1], 32);
#pragma unroll
    for (int qh = 0; qh < 2; qh++) {   // FULL unroll: static qh (rule #20)
        __syncthreads();  // qh=0: singer staging reads done; qh=1: round-0 done
        if (grp) {
#pragma unroll
            for (int dn = 0; dn < 2; dn++)
#pragma unroll
                for (int r = 0; r < 8; r++)
                    *(float2*)(p + dn * 16 + 2 * r) =
                        (float2){o[qh * 2 + dn][2 * r], o[qh * 2 + dn][2 * r + 1]};
            p[32] = li[qh];
        }
        __syncthreads();
        if (!grp) {
#pragma unroll
            for (int dn = 0; dn < 2; dn++)
#pragma unroll
                for (int r = 0; r < 16; r++) o[qh * 2 + dn][r] += p[dn * 16 + r];
            li[qh] += p[32];
            float inv[16];
#pragma unroll
            for (int rg = 0; rg < 16; rg++)
                inv[rg] = 1.f / __shfl(li[qh], (rg & 3) + 8 * (rg >> 2) + 4 * hi);
            // O: lane holds d = 32*dn + l5, q = q0 + qh*32 + crow(rg,hi)
#pragma unroll
            for (int dn = 0; dn < 2; dn++)
#pragma unroll
                for (int rg = 0; rg < 16; rg++) {
                    int qr = (rg & 3) + 8 * (rg >> 2) + 4 * hi;
                    float ov = yv[qh * 2 + dn][rg] + o[qh * 2 + dn][rg] * inv[rg];
                    y[(size_t)(bi * NQ + q0 + qh * 32 + qr) * DIM + h * 64 + 32 * dn + l5] = f2b(ov);
                }
        }
    }
}

extern "C" void kernel_launch(void* const* d_in, const int* in_sizes, int n_in,
                              void* d_out, int out_size, void* d_ws, size_t ws_size,
                              hipStream_t stream) {
    const float* x   = (const float*)d_in[0];
    const float* ac  = (const float*)d_in[1];
    const float* scx = (const float*)d_in[2];
    const float* Wq  = (const float*)d_in[3];
    const float* bq  = (const float*)d_in[4];
    const float* Wka = (const float*)d_in[5];
    const float* bka = (const float*)d_in[6];
    const float* Wva = (const float*)d_in[7];
    const float* bva = (const float*)d_in[8];
    const float* Wks = (const float*)d_in[9];
    const float* bks = (const float*)d_in[10];
    const float* Wvs = (const float*)d_in[11];
    const float* bvs = (const float*)d_in[12];
    const float* Wp  = (const float*)d_in[13];
    const float* bp  = (const float*)d_in[14];

    ushort* wb   = (ushort*)d_ws;         // contiguous cast dst:
    ushort* wqb  = wb;                    // [6 weights][xb][acb][scxb]
    ushort* wkab = wb + 262144;
    ushort* wvab = wb + 2 * 262144;
    ushort* wksb = wb + 3 * 262144;
    ushort* wvsb = wb + 4 * 262144;
    ushort* wpb  = wb + 5 * 262144;
    ushort* xb   = wb + 6 * 262144;       // [8192][512]
    ushort* acb  = xb + 4194304;          // [8192][512]
    ushort* scxb = acb + 4194304;         // [1024][512]
    ushort* qb   = scxb + 524288;         // [8192][512] prescaled q
    ushort* kab  = qb + 4194304;          // [8192][512]
    ushort* vta  = kab + 4194304;         // [4][512][2048] V^T
    ushort* ksb  = vta + 4194304;         // [1024][512]
    ushort* vts  = ksb + 524288;          // [4][512][256]  V^T
    ushort* yb   = xb;                    // alias: x dead after gemm_fused

    cast_all<<<10240, 256, 0, stream>>>(Wq, Wka, Wva, Wks, Wvs, Wp, x, ac, scx, wb);

    GD gq   = {xb,   wqb,  bq,  qb,  0, 0,               512,  64, 4,  0,   0, 1, 0, 0};
    GD gka  = {acb,  wkab, bka, kab, 0, 0,               512,  64, 4,  256, 0, 0, 0, 0};
    GD gvta = {wvab, acb,  bva, vta, 2048L * 512, 512L * 2048, 2048, 4, 16, 512, 1, 0, 0, 0};
    GD gks  = {scxb, wksb, bks, ksb, 0, 0,               512,  8,  4,  768, 0, 0, 0, 0};
    GD gvts = {wvsb, scxb, bvs, vts, 256L * 512, 512L * 256,   256,  4,  2,  800, 1, 0, 0, 0};
    gemm_fused<<<832, 256, 0, stream>>>(gq, gka, gvta, gks, gvts);

    attn_kernel<<<dim3(8, 8, 4), 512, 0, stream>>>(qb, kab, vta, ksb, vts, yb);

    GD gpr = {yb, wpb, bp, d_out, 0, 0, 512, 64, 4, 0, 0, 0, 1, 0};
    GD gnv = {nullptr, nullptr, nullptr, nullptr, 0, 0, 0, 1, 1, 1 << 30, 0, 0, 0, 0};
    gemm_fused<<<256, 256, 0, stream>>>(gpr, gnv, gnv, gnv, gnv);
}

// Round 12
// 223.672 us; speedup vs baseline: 1.0282x; 1.0282x over previous
//
#include <hip/hip_runtime.h>

// R19 == R11 (Round-4 kernel, byte-identical): the session's best-measured
// config (226.63us, passed). Ledger over 12 rounds resolved the pairing:
// rounds with THIS attn (64q DMA-staged, permc-folded V, VGPR=112) measured
// 226.63/226.65 (best two, 0.02us apart); R17's reg-staged attn rounds both
// 229.9; R9-attn rounds 227.4-228.3. Cold-replay profiles rank these
// INVERSELY (79us vs 58.8us) -- warm timed-graph conditions favor the lower
// instruction-count/VGPR variant and absorb its bank conflicts. Banking the
// minimum; reproduction run, no new risk.
#define DIM 512
#define NQ 2048
#define MA 2048
#define MS 256
#define QSCALE 0.06375864651f  // 512^-0.5 * log2(e)

typedef __attribute__((ext_vector_type(8))) short bf16x8;
typedef __attribute__((ext_vector_type(4))) float f32x4;
typedef __attribute__((ext_vector_type(16))) float f32x16;

__device__ __forceinline__ ushort f2b(float f) {
    uint u = __float_as_uint(f);
    u = (u + 0x7fffu + ((u >> 16) & 1u)) >> 16;
    return (ushort)u;
}

__device__ __forceinline__ uint pk2bf(float a, float b) {
#if __has_builtin(__builtin_amdgcn_cvt_pk_bf16_f32)
    typedef __attribute__((ext_vector_type(2))) __bf16 bf2;
    bf2 r = __builtin_amdgcn_cvt_pk_bf16_f32(a, b);
    uint u;
    __builtin_memcpy(&u, &r, 4);
    return u;
#else
    return ((__float_as_uint(a) + 0x8000u) >> 16) |
           ((__float_as_uint(b) + 0x8000u) & 0xffff0000u);
#endif
}

__device__ __forceinline__ float fexp2(float x) {
#if __has_builtin(__builtin_amdgcn_exp2f)
    return __builtin_amdgcn_exp2f(x);
#else
    return exp2f(x);
#endif
}

__device__ __forceinline__ void gload16(const ushort* g, ushort* l) {
    __builtin_amdgcn_global_load_lds(
        (const __attribute__((address_space(1))) void*)g,
        (__attribute__((address_space(3))) void*)l, 16, 0, 0);
}

// ---- fused cast: 6 weights + x + ac + scx -> contiguous bf16 region ----
__global__ __launch_bounds__(256) void cast_all(const float* __restrict__ w0,
                                                const float* __restrict__ w1,
                                                const float* __restrict__ w2,
                                                const float* __restrict__ w3,
                                                const float* __restrict__ w4,
                                                const float* __restrict__ w5,
                                                const float* __restrict__ x,
                                                const float* __restrict__ ac,
                                                const float* __restrict__ scx,
                                                ushort* __restrict__ dst) {
    int i = blockIdx.x * 256 + threadIdx.x;  // float4 index, 2621440 total
    const float* s;
    int o;
    if (i < 393216) {
        int w = i >> 16;
        s = w < 3 ? (w == 0 ? w0 : (w == 1 ? w1 : w2))
                  : (w == 3 ? w3 : (w == 4 ? w4 : w5));
        o = i & 65535;
    } else if (i < 1441792) { s = x;   o = i - 393216; }
    else if (i < 2490368)   { s = ac;  o = i - 1441792; }
    else                    { s = scx; o = i - 2490368; }
    float4 v = ((const float4*)s)[o];
    ushort4 u;
    u.x = f2b(v.x); u.y = f2b(v.y); u.z = f2b(v.z); u.w = f2b(v.w);
    ((ushort4*)dst)[i] = u;
}

// ---- fused GEMM: C = A @ B^T + bias, 128x128 tile, BK=32, LDS dbuf ----
// permc: permute output cols within each 16 (quad1<->quad2) -- pre-applies
// the attention PV ctx-permutation to V^T so attn can stage V linearly.
struct GD {
    const ushort* A; const ushort* B; const float* bias; void* out;
    long sB, sO;
    int N, bx, by, blk0, biasrow, scaleq, outf32, permc;
};

__global__ __launch_bounds__(256) void gemm_fused(GD d0, GD d1, GD d2, GD d3, GD d4) {
    __shared__ ushort At[2][128 * 32];
    __shared__ ushort Bt[2][128 * 32];
    GD d = d0;
    int bid = blockIdx.x;
    if (bid >= d1.blk0) d = d1;
    if (bid >= d2.blk0) d = d2;
    if (bid >= d3.blk0) d = d3;
    if (bid >= d4.blk0) d = d4;
    int local = bid - d.blk0;
    int x = local % d.bx;
    int rem = local / d.bx;
    int y = rem % d.by;
    int z = rem / d.by;

    int t = threadIdx.x;
    int wv = t >> 6, ln = t & 63, l = ln & 15, g = ln >> 4;
    int wrow = wv & 1, wcol = wv >> 1;
    int row0 = x * 128, col0 = y * 128;
    int srow = t >> 2;
    int slot = (t & 3) * 8;
    int sko = ((t ^ srow) & 3) * 8;        // XOR-swizzled global k-chunk
    int kc8 = ((g ^ (l & 3)) & 3) * 8;     // reader un-swizzle
    int l4 = (l >> 2) & 3;
    int lp = d.permc ? (l4 == 1 ? l + 4 : (l4 == 2 ? l - 4 : l)) : l;
    const ushort* Ab = d.A;
    const ushort* Bb = d.B + (size_t)z * d.sB;
    int N = d.N;

    const ushort* Ar0 = Ab + (size_t)(row0 + srow) * 512 + sko;
    const ushort* Ar1 = Ab + (size_t)(row0 + srow + 64) * 512 + sko;
    const ushort* Br0 = Bb + (size_t)(col0 + srow) * 512 + sko;
    const ushort* Br1 = Bb + (size_t)(col0 + srow + 64) * 512 + sko;
    int so0 = srow * 32 + slot;
    int so1 = (srow + 64) * 32 + slot;

    f32x4 acc[4][4];
#pragma unroll
    for (int i = 0; i < 4; i++)
#pragma unroll
        for (int j = 0; j < 4; j++) acc[i][j] = (f32x4){0, 0, 0, 0};

    // prologue: stage K-step 0 into buf 0
    gload16(Ar0, At[0] + so0);
    gload16(Ar1, At[0] + so1);
    gload16(Br0, Bt[0] + so0);
    gload16(Br1, Bt[0] + so1);

#pragma unroll 2
    for (int k0 = 0; k0 < 512; k0 += 32) {
        int cur = (k0 >> 5) & 1;
        __syncthreads();  // drains loads issued one compute-phase ago
        if (k0 + 32 < 512) {  // issue next tile BEFORE computing current
            gload16(Ar0 + k0 + 32, At[cur ^ 1] + so0);
            gload16(Ar1 + k0 + 32, At[cur ^ 1] + so1);
            gload16(Br0 + k0 + 32, Bt[cur ^ 1] + so0);
            gload16(Br1 + k0 + 32, Bt[cur ^ 1] + so1);
        }
        bf16x8 ar[4], br[4];
#pragma unroll
        for (int i = 0; i < 4; i++)
            ar[i] = *(const bf16x8*)(At[cur] + (wrow * 64 + i * 16 + l) * 32 + kc8);
#pragma unroll
        for (int j = 0; j < 4; j++)
            br[j] = *(const bf16x8*)(Bt[cur] + (wcol * 64 + j * 16 + l) * 32 + kc8);
#pragma unroll
        for (int i = 0; i < 4; i++)
#pragma unroll
            for (int j = 0; j < 4; j++)
                acc[i][j] = __builtin_amdgcn_mfma_f32_16x16x32_bf16(ar[i], br[j], acc[i][j], 0, 0, 0);
    }
#pragma unroll
    for (int i = 0; i < 4; i++) {
#pragma unroll
        for (int j = 0; j < 4; j++) {
            int row = row0 + wrow * 64 + i * 16 + g * 4;
            int col = col0 + wcol * 64 + j * 16 + lp;
#pragma unroll
            for (int r = 0; r < 4; r++) {
                float bv = d.biasrow ? d.bias[row + r] : d.bias[col];
                float o = acc[i][j][r] + bv;
                if (d.scaleq) o *= QSCALE;
                if (d.outf32)
                    ((float*)d.out + (size_t)z * d.sO)[(size_t)(row + r) * N + col] = o;
                else
                    ((ushort*)d.out + (size_t)z * d.sO)[(size_t)(row + r) * N + col] = f2b(o);
            }
        }
    }
}

// ---- attention inner loop: 64 q-rows/wave, DMA-staged K/V, dbuf ----
// LDS K/V tiles linear [64][64] ushort; XOR swizzle (r&7)*8 ushorts applied to
// the DMA *source* column and the ds_read column (both-sides involution).
// V^T in global is pre-permuted (gvta/gvts permc) so each lane's P quads are
// its own PV A-frag slots; B k-slot j then reads LDS pos kc*16+hi*8+j linear.
__device__ __forceinline__ void attn_64q(const ushort* __restrict__ kgb,
                                         const ushort* __restrict__ vgb,
                                         int M, int nt, const bf16x8 (&aq)[2][4],
                                         ushort* __restrict__ Kl,   // 2*4096 dbuf
                                         ushort* __restrict__ Vl,
                                         f32x16 (&o)[4], float (&li)[2],
                                         int l5, int hi, int w, int ln) {
    int r8 = ln >> 3;
    int cc = 8 * ((ln & 7) ^ r8);          // inverse-swizzled source chunk
    const ushort* ks0 = kgb + (size_t)(w * 16 + r8) * DIM + cc;
    const ushort* vs0 = vgb + (size_t)(w * 16 + r8) * M + cc;
    int rx = (l5 & 7) * 8;                 // reader swizzle
    int hb = hi * 8;
    // prologue: stage tile 0 -> buf 0 (4 x global_load_lds, wave covers 16 rows)
    gload16(ks0, Kl + w * 1024);
    gload16(ks0 + (size_t)8 * DIM, Kl + w * 1024 + 512);
    gload16(vs0, Vl + w * 1024);
    gload16(vs0 + (size_t)8 * M, Vl + w * 1024 + 512);
    for (int i = 0; i < nt; i++) {
        __syncthreads();  // drains my DMAs (issued a full tile ago) + buf reuse
        if (i + 1 < nt) {
            const ushort* ks = ks0 + (size_t)(i + 1) * 64 * DIM;
            const ushort* vs = vs0 + (size_t)(i + 1) * 64;
            ushort* Kb = Kl + ((i + 1) & 1) * 4096;
            ushort* Vb = Vl + ((i + 1) & 1) * 4096;
            gload16(ks, Kb + w * 1024);
            gload16(ks + (size_t)8 * DIM, Kb + w * 1024 + 512);
            gload16(vs, Vb + w * 1024);
            gload16(vs + (size_t)8 * M, Vb + w * 1024 + 512);
        }
        const ushort* Kc = Kl + (i & 1) * 4096;
        const ushort* Vc = Vl + (i & 1) * 4096;
        uint2 pq[2][2][4];
#pragma unroll
        for (int c = 0; c < 2; c++) {
            bf16x8 kf[4];
#pragma unroll
            for (int kd = 0; kd < 4; kd++)
                kf[kd] = *(const bf16x8*)(Kc + (32 * c + l5) * 64 + ((kd * 16 + hb) ^ rx));
#pragma unroll
            for (int qh = 0; qh < 2; qh++) {
                f32x16 s;
#pragma unroll
                for (int ii = 0; ii < 16; ii++) s[ii] = 0.f;
                __builtin_amdgcn_s_setprio(1);
#pragma unroll
                for (int kd = 0; kd < 4; kd++)
                    s = __builtin_amdgcn_mfma_f32_32x32x16_bf16(kf[kd], aq[qh][kd], s, 0, 0, 0);
                __builtin_amdgcn_s_setprio(0);
#pragma unroll
                for (int m = 0; m < 4; m++) {
                    float p0 = fexp2(s[4 * m + 0]);
                    float p1 = fexp2(s[4 * m + 1]);
                    float p2 = fexp2(s[4 * m + 2]);
                    float p3 = fexp2(s[4 * m + 3]);
                    li[qh] += (p0 + p1) + (p2 + p3);
                    pq[qh][c][m].x = pk2bf(p0, p1);
                    pq[qh][c][m].y = pk2bf(p2, p3);
                }
            }
        }
#pragma unroll
        for (int kc = 0; kc < 4; kc++) {
            int c = kc >> 1, m0 = 2 * (kc & 1);
            bf16x8 vf0 = *(const bf16x8*)(Vc + l5 * 64 + ((kc * 16 + hb) ^ rx));
            bf16x8 vf1 = *(const bf16x8*)(Vc + (32 + l5) * 64 + ((kc * 16 + hb) ^ rx));
            __builtin_amdgcn_s_setprio(1);
#pragma unroll
            for (int qh = 0; qh < 2; qh++) {
                union { bf16x8 v; uint u[4]; } wv;
                wv.u[0] = pq[qh][c][m0].x;     wv.u[1] = pq[qh][c][m0].y;
                wv.u[2] = pq[qh][c][m0 + 1].x; wv.u[3] = pq[qh][c][m0 + 1].y;
                o[qh * 2 + 0] = __builtin_amdgcn_mfma_f32_32x32x16_bf16(wv.v, vf0, o[qh * 2 + 0], 0, 0, 0);
                o[qh * 2 + 1] = __builtin_amdgcn_mfma_f32_32x32x16_bf16(wv.v, vf1, o[qh * 2 + 1], 0, 0, 0);
            }
            __builtin_amdgcn_s_setprio(0);
        }
    }
}

// 512 threads: grp = ctx half, wave w (0..3) = q rows [bx*256+w*64, +64).
// LDS: A = staging (2 grp x (K 8KB dbuf | V 8KB dbuf)) = 64KB;
//      B = exchange/park region, 256 thr x 68 floats = 68KB.  Total 132KB.
// Flow: audio -> grp1 ships (o,li) via B -> grp0 combines+normalizes, parks
// result back in B -> both run singer -> grp1 ships via A (staging dead) +
// li via B spare -> grp0 combines, adds parked audio, writes y.
__global__ __launch_bounds__(512) void attn_kernel(const ushort* __restrict__ q,
                                                   const ushort* __restrict__ Ka,
                                                   const ushort* __restrict__ VTa,
                                                   const ushort* __restrict__ Ks,
                                                   const ushort* __restrict__ VTs,
                                                   ushort* __restrict__ y) {
    __shared__ ushort smem[67584];  // 65536B staging + 69632B exchange/park
    int t = threadIdx.x;
    int grp = t >> 8;
    int tg = t & 255;
    int w = (t >> 6) & 3;
    int ln = t & 63, l5 = ln & 31, hi = ln >> 5;
    ushort* Kl = smem + grp * 16384;
    ushort* Vl = Kl + 8192;
    float* Bx = (float*)(smem + 32768);
    float* Ax = (float*)smem;
    int h = blockIdx.y, bi = blockIdx.z;
    int q0w = blockIdx.x * 256 + w * 64;

    bf16x8 aq[2][4];
#pragma unroll
    for (int qh = 0; qh < 2; qh++) {
        const ushort* qp = q + (size_t)(bi * NQ + q0w + qh * 32 + l5) * DIM + h * 64 + hi * 8;
#pragma unroll
        for (int kd = 0; kd < 4; kd++) aq[qh][kd] = *(const bf16x8*)(qp + kd * 16);
    }

    f32x16 o[4];
#pragma unroll
    for (int k = 0; k < 4; k++)
#pragma unroll
        for (int i = 0; i < 16; i++) o[k][i] = 0.f;
    float li[2] = {0.f, 0.f};

    // audio: group grp handles ctx [grp*1024, grp*1024+1024)
    attn_64q(Ka + (size_t)bi * MA * DIM + (size_t)(grp * 1024) * DIM + h * 64,
             VTa + (size_t)bi * DIM * MA + (size_t)(h * 64) * MA + grp * 1024,
             MA, 16, aq, Kl, Vl, o, li, l5, hi, w, ln);
    li[0] += __shfl_xor(li[0], 32);
    li[1] += __shfl_xor(li[1], 32);
    __syncthreads();  // all staging reads done
    float* slot = Bx + tg * 68;
    if (grp) {
#pragma unroll
        for (int k = 0; k < 4; k++)
#pragma unroll
            for (int r = 0; r < 8; r++)
                *(float2*)(slot + k * 16 + 2 * r) = (float2){o[k][2 * r], o[k][2 * r + 1]};
        slot[64] = li[0];
        slot[65] = li[1];
    }
    __syncthreads();
    if (!grp) {
#pragma unroll
        for (int k = 0; k < 4; k++)
#pragma unroll
            for (int r = 0; r < 16; r++) o[k][r] += slot[k * 16 + r];
        li[0] += slot[64];
        li[1] += slot[65];
#pragma unroll
        for (int qh = 0; qh < 2; qh++) {
            float inv[16];
#pragma unroll
            for (int rg = 0; rg < 16; rg++)
                inv[rg] = 1.f / __shfl(li[qh], (rg & 3) + 8 * (rg >> 2) + 4 * hi);
#pragma unroll
            for (int dn = 0; dn < 2; dn++)
#pragma unroll
                for (int rg = 0; rg < 16; rg++) o[qh * 2 + dn][rg] *= inv[rg];
        }
        // park normalized audio result (frees the o regs for singer)
#pragma unroll
        for (int k = 0; k < 4; k++)
#pragma unroll
            for (int r = 0; r < 8; r++)
                *(float2*)(slot + k * 16 + 2 * r) = (float2){o[k][2 * r], o[k][2 * r + 1]};
    }

#pragma unroll
    for (int k = 0; k < 4; k++)
#pragma unroll
        for (int i = 0; i < 16; i++) o[k][i] = 0.f;
    li[0] = li[1] = 0.f;
    // singer: group grp handles ctx [grp*128, grp*128+128)
    attn_64q(Ks + (size_t)bi * MS * DIM + (size_t)(grp * 128) * DIM + h * 64,
             VTs + (size_t)bi * DIM * MS + (size_t)(h * 64) * MS + grp * 128,
             MS, 2, aq, Kl, Vl, o, li, l5, hi, w, ln);
    li[0] += __shfl_xor(li[0], 32);
    li[1] += __shfl_xor(li[1], 32);
    __syncthreads();  // singer staging reads done; A region free
    float* As = Ax + tg * 64;
    if (grp) {
#pragma unroll
        for (int k = 0; k < 4; k++)
#pragma unroll
            for (int r = 0; r < 8; r++)
                *(float2*)(As + k * 16 + 2 * r) = (float2){o[k][2 * r], o[k][2 * r + 1]};
        slot[66] = li[0];
        slot[67] = li[1];
    }
    __syncthreads();
    if (!grp) {
#pragma unroll
        for (int k = 0; k < 4; k++)
#pragma unroll
            for (int r = 0; r < 16; r++) o[k][r] += As[k * 16 + r];
        li[0] += slot[66];
        li[1] += slot[67];
#pragma unroll
        for (int qh = 0; qh < 2; qh++) {
            float inv[16];
#pragma unroll
            for (int rg = 0; rg < 16; rg++)
                inv[rg] = 1.f / __shfl(li[qh], (rg & 3) + 8 * (rg >> 2) + 4 * hi);
#pragma unroll
            for (int dn = 0; dn < 2; dn++)
#pragma unroll
                for (int rg = 0; rg < 16; rg++) {
                    int qr = (rg & 3) + 8 * (rg >> 2) + 4 * hi;
                    float ov = slot[(qh * 2 + dn) * 16 + rg] + o[qh * 2 + dn][rg] * inv[rg];
                    y[(size_t)(bi * NQ + q0w + qh * 32 + qr) * DIM + h * 64 + 32 * dn + l5] = f2b(ov);
                }
        }
    }
}

extern "C" void kernel_launch(void* const* d_in, const int* in_sizes, int n_in,
                              void* d_out, int out_size, void* d_ws, size_t ws_size,
                              hipStream_t stream) {
    const float* x   = (const float*)d_in[0];
    const float* ac  = (const float*)d_in[1];
    const float* scx = (const float*)d_in[2];
    const float* Wq  = (const float*)d_in[3];
    const float* bq  = (const float*)d_in[4];
    const float* Wka = (const float*)d_in[5];
    const float* bka = (const float*)d_in[6];
    const float* Wva = (const float*)d_in[7];
    const float* bva = (const float*)d_in[8];
    const float* Wks = (const float*)d_in[9];
    const float* bks = (const float*)d_in[10];
    const float* Wvs = (const float*)d_in[11];
    const float* bvs = (const float*)d_in[12];
    const float* Wp  = (const float*)d_in[13];
    const float* bp  = (const float*)d_in[14];

    ushort* wb   = (ushort*)d_ws;         // contiguous cast dst:
    ushort* wqb  = wb;                    // [6 weights][xb][acb][scxb]
    ushort* wkab = wb + 262144;
    ushort* wvab = wb + 2 * 262144;
    ushort* wksb = wb + 3 * 262144;
    ushort* wvsb = wb + 4 * 262144;
    ushort* wpb  = wb + 5 * 262144;
    ushort* xb   = wb + 6 * 262144;       // [8192][512]
    ushort* acb  = xb + 4194304;          // [8192][512]
    ushort* scxb = acb + 4194304;         // [1024][512]
    ushort* qb   = scxb + 524288;         // [8192][512] prescaled q
    ushort* kab  = qb + 4194304;          // [8192][512]
    ushort* vta  = kab + 4194304;         // [4][512][2048] V^T (ctx-permuted)
    ushort* ksb  = vta + 4194304;         // [1024][512]
    ushort* vts  = ksb + 524288;          // [4][512][256]  V^T (ctx-permuted)
    ushort* yb   = xb;                    // alias: x dead after gemm_fused

    cast_all<<<10240, 256, 0, stream>>>(Wq, Wka, Wva, Wks, Wvs, Wp, x, ac, scx, wb);

    GD gq   = {xb,   wqb,  bq,  qb,  0, 0,               512,  64, 4,  0,   0, 1, 0, 0};
    GD gka  = {acb,  wkab, bka, kab, 0, 0,               512,  64, 4,  256, 0, 0, 0, 0};
    GD gvta = {wvab, acb,  bva, vta, 2048L * 512, 512L * 2048, 2048, 4, 16, 512, 1, 0, 0, 1};
    GD gks  = {scxb, wksb, bks, ksb, 0, 0,               512,  8,  4,  768, 0, 0, 0, 0};
    GD gvts = {wvsb, scxb, bvs, vts, 256L * 512, 512L * 256,   256,  4,  2,  800, 1, 0, 0, 1};
    gemm_fused<<<832, 256, 0, stream>>>(gq, gka, gvta, gks, gvts);

    attn_kernel<<<dim3(8, 8, 4), 512, 0, stream>>>(qb, kab, vta, ksb, vts, yb);

    GD gpr = {yb, wpb, bp, d_out, 0, 0, 512, 64, 4, 0, 0, 0, 1, 0};
    GD gnv = {nullptr, nullptr, nullptr, nullptr, 0, 0, 0, 1, 1, 1 << 30, 0, 0, 0, 0};
    gemm_fused<<<256, 256, 0, stream>>>(gpr, gnv, gnv, gnv, gnv);
}